// Round 5
// baseline (233.434 us; speedup 1.0000x reference)
//
#include <hip/hip_runtime.h>

// RoDAlignMax: features [4,256,64,64] f32, rois [2048,5] f32 -> out [2048,256,9,9] f32
// Grid coords are exactly (7i,7j) (63/9==7 in fp32) => bilinear degenerates to a
// gather; in-ROI samples are zeroed before the 2x2/s1 maxpool.
//
// A window (i,j) is affected by the ROI only if hb=(inh>>i)&3 and wb=(inw>>j)&3 are
// both nonzero (~15% of windows on average). Otherwise output = plain maxpool M.
//   masked result = max(rowCand, colCand, 0):
//     rowCand = (hb==1)?r1:(hb==2)?r0:0 ; colCand = (wb==1)?c1:(wb==2)?c0:0
//
// K1: M4[bc*81+q] = plain pool (332 KB -> d_ws, known-safe size);
//     T16[bc*81+q] = (r0,r1,c0,c1)  (1.33 MB -> parked in the LAST 16 ROIs of d_out)
// K2: rois 0..2031: per 4 outputs: 1x dwordx4 M-load + LDS LUT + rare 16B T16 fixup,
//     dwordx4 coalesced stores. K3: rois 2032..2047 (the T16 parking spot),
//     fixup recomputed from F directly; runs after K2 -> no race.

typedef float f4 __attribute__((ext_vector_type(4)));

#define NQ 81
#define NPR 20736            // elements per roi = 256*81
#define TAIL_BASE 2032       // T16 lives in out[TAIL_BASE*NPR ..]

__global__ __launch_bounds__(256) void rod_tables(const float* __restrict__ F,
                                                  float* __restrict__ M4,
                                                  f4* __restrict__ T16) {
    int idx = blockIdx.x * 256 + threadIdx.x;          // < 82944 = 1024*81
    if (idx < 82944) {
        unsigned bc = ((unsigned)idx * 25891u) >> 21;  // idx/81
        int q = idx - 81 * (int)bc;
        int i = (q * 57) >> 9;                         // q/9
        int j = q - 9 * i;
        const float* fp = F + ((int)bc << 12) + i * 448 + j * 7;  // F[b,c,7i,7j]
        float v00 = fp[0], v01 = fp[7], v10 = fp[448], v11 = fp[455];
        f4 t;
        t.x = fmaxf(v00, v01);   // r0
        t.y = fmaxf(v10, v11);   // r1
        t.z = fmaxf(v00, v10);   // c0
        t.w = fmaxf(v01, v11);   // c1
        T16[idx] = t;
        M4[idx] = fmaxf(t.x, t.y);
    }
}

__device__ __forceinline__ void roi_masks(const float* __restrict__ rois, int r,
                                          unsigned& inh, unsigned& inw, int& b) {
    float x1 = rois[r * 5 + 1] * 0.25f, y1 = rois[r * 5 + 2] * 0.25f;
    float x2 = rois[r * 5 + 3] * 0.25f, y2 = rois[r * 5 + 4] * 0.25f;
    b = (int)rois[r * 5 + 0];
    inh = 0u; inw = 0u;
    #pragma unroll
    for (int t = 0; t < 10; ++t) {
        float s = 7.0f * (float)t;                     // exact grid coordinate
        if (s >= y1 && s <= y2) inh |= 1u << t;
        if (s >= x1 && s <= x2) inw |= 1u << t;
    }
}

__device__ __forceinline__ void build_lut(unsigned* lut, int tid,
                                          unsigned inh, unsigned inw) {
    if (tid < NQ) {
        int i = (tid * 57) >> 9;
        int j = tid - 9 * i;
        unsigned hb = (inh >> i) & 3u, wb = (inw >> j) & 3u;
        lut[tid] = (hb && wb) ? ((hb << 2) | wb) : 0u;
    }
}

__device__ __forceinline__ float fix_from_t(f4 t, unsigned sel) {
    unsigned hb = sel >> 2, wb = sel & 3u;
    float rowA = (hb == 1u) ? t.y : ((hb == 2u) ? t.x : 0.0f);
    float colA = (wb == 1u) ? t.w : ((wb == 2u) ? t.z : 0.0f);
    return fmaxf(fmaxf(rowA, colA), 0.0f);
}

__global__ __launch_bounds__(256, 8) void rod_main5(const float* __restrict__ M4,
                                                    const f4* __restrict__ T16,
                                                    const float* __restrict__ rois,
                                                    float* __restrict__ out) {
    __shared__ unsigned lut[NQ];
    const int tid = threadIdx.x;
    const int r = blockIdx.x;
    unsigned inh, inw; int b;
    roi_masks(rois, r, inh, inw, b);
    build_lut(lut, tid, inh, inw);
    __syncthreads();

    const float* Mb = M4 + b * NPR;
    const f4*    Tb = T16 + b * NPR;                 // f4 index = flat c*81+q
    float*       dst = out + (size_t)r * NPR;

    int e  = tid * 4;
    int q0 = e - 81 * (int)(((unsigned)e * 25891u) >> 21);   // e % 81

    #pragma unroll 4
    for (int k = 0; k < 20; ++k) {                   // e max = 20476 < 20736
        f4 m = *(const f4*)(Mb + e);
        float res[4];
        #pragma unroll
        for (int ii = 0; ii < 4; ++ii) {
            int qi = q0 + ii; qi = (qi >= NQ) ? qi - NQ : qi;
            unsigned sel = lut[qi];
            float v = m[ii];
            if (sel) v = fix_from_t(Tb[e + ii], sel);
            res[ii] = v;
        }
        *(f4*)(dst + e) = (f4){res[0], res[1], res[2], res[3]};
        e += 1024;
        q0 += 52; q0 = (q0 >= NQ) ? q0 - NQ : q0;    // 1024 % 81 == 52
    }
    if (tid < 64) {                                  // tail: e in [20480, 20736)
        f4 m = *(const f4*)(Mb + e);
        float res[4];
        #pragma unroll
        for (int ii = 0; ii < 4; ++ii) {
            int qi = q0 + ii; qi = (qi >= NQ) ? qi - NQ : qi;
            unsigned sel = lut[qi];
            float v = m[ii];
            if (sel) v = fix_from_t(Tb[e + ii], sel);
            res[ii] = v;
        }
        *(f4*)(dst + e) = (f4){res[0], res[1], res[2], res[3]};
    }
}

__global__ __launch_bounds__(256) void rod_tail(const float* __restrict__ M4,
                                                const float* __restrict__ F,
                                                const float* __restrict__ rois,
                                                float* __restrict__ out) {
    __shared__ unsigned lut[NQ];
    const int tid = threadIdx.x;
    const int r = TAIL_BASE + blockIdx.x;
    unsigned inh, inw; int b;
    roi_masks(rois, r, inh, inw, b);
    build_lut(lut, tid, inh, inw);
    __syncthreads();

    const float* Mb = M4 + b * NPR;
    const float* Fb = F + ((size_t)b << 20);         // b*256*64*64
    float*       dst = out + (size_t)r * NPR;

    int e  = tid * 4;
    int q0 = e - 81 * (int)(((unsigned)e * 25891u) >> 21);

    for (int k = 0; k < 21; ++k) {
        if (e < NPR) {
            f4 m = *(const f4*)(Mb + e);
            float res[4];
            #pragma unroll
            for (int ii = 0; ii < 4; ++ii) {
                int qi = q0 + ii; qi = (qi >= NQ) ? qi - NQ : qi;
                unsigned sel = lut[qi];
                float v = m[ii];
                if (sel) {                           // recompute window from F
                    int c = (int)(((unsigned)(e + ii) * 25891u) >> 21);
                    int i = (qi * 57) >> 9;
                    int j = qi - 9 * i;
                    const float* fp = Fb + (c << 12) + i * 448 + j * 7;
                    float v00 = fp[0], v01 = fp[7], v10 = fp[448], v11 = fp[455];
                    f4 t;
                    t.x = fmaxf(v00, v01); t.y = fmaxf(v10, v11);
                    t.z = fmaxf(v00, v10); t.w = fmaxf(v01, v11);
                    v = fix_from_t(t, sel);
                }
                res[ii] = v;
            }
            *(f4*)(dst + e) = (f4){res[0], res[1], res[2], res[3]};
        }
        e += 1024;
        q0 += 52; q0 = (q0 >= NQ) ? q0 - NQ : q0;
    }
}

extern "C" void kernel_launch(void* const* d_in, const int* in_sizes, int n_in,
                              void* d_out, int out_size, void* d_ws, size_t ws_size,
                              hipStream_t stream) {
    const float* F    = (const float*)d_in[0];   // 4*256*64*64
    const float* rois = (const float*)d_in[1];   // 2048*5
    float*       out  = (float*)d_out;           // 2048*256*81
    float*       M4   = (float*)d_ws;            // 82944*4 B = 331,776 B (known-safe)
    f4*          T16  = (f4*)(out + (size_t)TAIL_BASE * NPR);  // 82944*16 B, out tail

    rod_tables<<<dim3(324),  dim3(256), 0, stream>>>(F, M4, T16);
    rod_main5 <<<dim3(2032), dim3(256), 0, stream>>>(M4, T16, rois, out);
    rod_tail  <<<dim3(16),   dim3(256), 0, stream>>>(M4, F, rois, out);
}